// Round 5
// baseline (538.645 us; speedup 1.0000x reference)
//
#include <hip/hip_runtime.h>

#define N_IMG_D 150528   // 3*224*224
#define CH_STRIDE 50176  // 224*224

// ---------------------------------------------------------------------------
// Kernel 1: patchify + linear embed + positional embedding.
// grid = n_images*16 (one block per image per patch-row py), block = 256.
// tokens[n, py*16+px, e] = sum_k images[n,c,py*14+r,px*14+col] * Wm[k][e] + bm[e]
//   with k = c*196 + r*14 + col.  Writes x rows 1..256 (with pe added) to ws.
// ---------------------------------------------------------------------------
__global__ __launch_bounds__(256) void k_patch_embed(
    const float* __restrict__ img, const float* __restrict__ Wm,
    const float* __restrict__ bm, const float* __restrict__ pe,
    float* __restrict__ xws)
{
    __shared__ __align__(16) float wmA[588 * 4];   // Wm[k][0..3]
    __shared__ __align__(16) float wmB[588 * 4];   // Wm[k][4..7]
    __shared__ __align__(16) float red[224 * 8];

    const int t = threadIdx.x;
    const int b = blockIdx.x;
    const int n = b >> 4, py = b & 15;

    // Stage Wm into two LDS planes (split breaks the 32B-stride bank aliasing
    // that a [588][8] layout would give on the paired float4 reads below).
    for (int i = t; i < 1176; i += 256) {           // 1176 float4 = 588*8 floats
        float4 w = reinterpret_cast<const float4*>(Wm)[i];
        float* dst = (i & 1) ? wmB : wmA;
        *reinterpret_cast<float4*>(dst + (i >> 1) * 4) = w;
    }
    __syncthreads();

    if (t < 224) {
        const int rp = t / 112;          // row parity (0/1)
        const int t1 = t - rp * 112;
        const int px = t1 / 7;           // patch column 0..15
        const int j  = t1 - px * 7;      // col pair 0..6
        const int col0 = 2 * j;
        const float* ib = img + (size_t)n * N_IMG_D + (py * 14) * 224 + px * 14 + col0;
        float a0=0,a1=0,a2=0,a3=0,a4=0,a5=0,a6=0,a7=0;
        // flat = c*14 + r walks rp, rp+2, ..., rp+40; track (c,r) incrementally.
        int c = 0, r = rp;
        const float* wA = wmA + (rp * 14 + col0) * 4;   // k = flat*14 + col0
        const float* wB = wmB + (rp * 14 + col0) * 4;
        #pragma unroll
        for (int it = 0; it < 21; ++it) {
            const float2 v = *reinterpret_cast<const float2*>(ib + c * CH_STRIDE + r * 224);
            const float4 wa0 = *reinterpret_cast<const float4*>(wA);
            const float4 wa1 = *reinterpret_cast<const float4*>(wA + 4);
            const float4 wb0 = *reinterpret_cast<const float4*>(wB);
            const float4 wb1 = *reinterpret_cast<const float4*>(wB + 4);
            a0 += v.x * wa0.x + v.y * wa1.x;
            a1 += v.x * wa0.y + v.y * wa1.y;
            a2 += v.x * wa0.z + v.y * wa1.z;
            a3 += v.x * wa0.w + v.y * wa1.w;
            a4 += v.x * wb0.x + v.y * wb1.x;
            a5 += v.x * wb0.y + v.y * wb1.y;
            a6 += v.x * wb0.z + v.y * wb1.z;
            a7 += v.x * wb0.w + v.y * wb1.w;
            r += 2;
            if (r >= 14) { r -= 14; c += 1; }
            wA += 28 * 4; wB += 28 * 4;               // flat advances by 2 → k by 28
        }
        *reinterpret_cast<float4*>(red + t * 8)     = make_float4(a0, a1, a2, a3);
        *reinterpret_cast<float4*>(red + t * 8 + 4) = make_float4(a4, a5, a6, a7);
    }
    __syncthreads();

    if (t < 128) {                       // 16 patches x 8 outputs
        const int px = t >> 3, e = t & 7;
        float s = 0.f;
        #pragma unroll
        for (int rp = 0; rp < 2; ++rp) {
            #pragma unroll
            for (int j = 0; j < 7; ++j)
                s += red[(rp * 112 + px * 7 + j) * 8 + e];
        }
        const int row = 1 + py * 16 + px;
        s += bm[e] + pe[row * 8 + e];
        xws[((size_t)n * 257 + row) * 8 + e] = s;   // coalesced: 128 consecutive floats
    }
}

// ---------------------------------------------------------------------------
// Kernel 2: cls token + 2 transformer layers + head, one block per image.
// block = 576 threads (covers 514 = 2 heads * 257 rows attention items).
// ---------------------------------------------------------------------------
__global__ __launch_bounds__(576) void k_transformer(
    const float* __restrict__ xws, const int* __restrict__ labels,
    const float* __restrict__ cls_table, const float* __restrict__ pe,
    const float* __restrict__ ln1_g, const float* __restrict__ ln1_b,
    const float* __restrict__ Wq, const float* __restrict__ bq,
    const float* __restrict__ Wk, const float* __restrict__ bk,
    const float* __restrict__ Wv, const float* __restrict__ bv,
    const float* __restrict__ ln2_g, const float* __restrict__ ln2_b,
    const float* __restrict__ W1, const float* __restrict__ b1,
    const float* __restrict__ W2, const float* __restrict__ b2,
    const float* __restrict__ Wf, const float* __restrict__ bf,
    float* __restrict__ out)
{
    __shared__ __align__(16) float xb[257 * 9];       // x, row-padded to 9
    __shared__ __align__(16) float hb[257 * 9];       // layernorm output
    __shared__ __align__(16) float kb[2 * 257 * 4];   // k, float4 rows
    __shared__ __align__(16) float vb[2 * 257 * 4];   // v, float4 rows
    __shared__ float wqs[64], wks[64], wvs[64];
    __shared__ float bqs[16], bks[16], bvs[16];
    __shared__ float w1s[512], b1s[64], w2s[512], b2s[16];

    const int t = threadIdx.x;
    const int n = blockIdx.x;
    const float* xn = xws + (size_t)n * 2056;

    // Stage all small weights (once per block).
    for (int i = t; i < 64; i += 576) { wqs[i] = Wq[i]; wks[i] = Wk[i]; wvs[i] = Wv[i]; b1s[i] = b1[i]; }
    for (int i = t; i < 16; i += 576) { bqs[i] = bq[i]; bks[i] = bk[i]; bvs[i] = bv[i]; b2s[i] = b2[i]; }
    for (int i = t; i < 512; i += 576) { w1s[i] = W1[i]; w2s[i] = W2[i]; }

    // Load x rows 1..256 from ws (float4), build cls row 0.
    if (t < 512) {
        float4 v = reinterpret_cast<const float4*>(xn)[t + 2];   // floats 8..2055
        const int s = (t + 2) >> 1;
        const int e0 = (t & 1) ? 4 : 0;
        float* d = xb + s * 9 + e0;
        d[0] = v.x; d[1] = v.y; d[2] = v.z; d[3] = v.w;
    } else if (t < 520) {
        const int e = t - 512;
        xb[e] = cls_table[labels[n] * 8 + e] + pe[e];
    }
    __syncthreads();

    for (int l = 0; l < 2; ++l) {
        // ---- LN1 ----
        if (t < 257) {
            float v0[8]; float m = 0.f;
            #pragma unroll
            for (int e = 0; e < 8; ++e) { v0[e] = xb[t * 9 + e]; m += v0[e]; }
            m *= 0.125f;
            float var = 0.f;
            #pragma unroll
            for (int e = 0; e < 8; ++e) { float d = v0[e] - m; var += d * d; }
            var *= 0.125f;
            const float rs = rsqrtf(var + 1e-5f);
            const float* g = ln1_g + l * 8; const float* bb = ln1_b + l * 8;
            #pragma unroll
            for (int e = 0; e < 8; ++e) hb[t * 9 + e] = (v0[e] - m) * rs * g[e] + bb[e];
        }
        __syncthreads();

        // ---- K,V projections ----
        if (t < 514) {
            const int h = (t >= 257) ? 1 : 0;
            const int s = t - 257 * h;
            float hv[4];
            #pragma unroll
            for (int d = 0; d < 4; ++d) hv[d] = hb[s * 9 + h * 4 + d];
            const float* wk = wks + (l * 2 + h) * 16; const float* bk_ = bks + (l * 2 + h) * 4;
            const float* wv = wvs + (l * 2 + h) * 16; const float* bv_ = bvs + (l * 2 + h) * 4;
            float kk[4], vv[4];
            #pragma unroll
            for (int e = 0; e < 4; ++e) { kk[e] = bk_[e]; vv[e] = bv_[e]; }
            #pragma unroll
            for (int d = 0; d < 4; ++d)
                #pragma unroll
                for (int e = 0; e < 4; ++e) {
                    kk[e] += hv[d] * wk[d * 4 + e];
                    vv[e] += hv[d] * wv[d * 4 + e];
                }
            *reinterpret_cast<float4*>(kb + (h * 257 + s) * 4) = make_float4(kk[0], kk[1], kk[2], kk[3]);
            *reinterpret_cast<float4*>(vb + (h * 257 + s) * 4) = make_float4(vv[0], vv[1], vv[2], vv[3]);
        }
        __syncthreads();

        // ---- Attention (online softmax, no max: scores bounded << 88) ----
        if (t < 514) {
            const int h = (t >= 257) ? 1 : 0;
            const int s = t - 257 * h;
            float hv[4];
            #pragma unroll
            for (int d = 0; d < 4; ++d) hv[d] = hb[s * 9 + h * 4 + d];
            const float* wq = wqs + (l * 2 + h) * 16; const float* bq_ = bqs + (l * 2 + h) * 4;
            float q[4];
            #pragma unroll
            for (int e = 0; e < 4; ++e) q[e] = bq_[e];
            #pragma unroll
            for (int d = 0; d < 4; ++d)
                #pragma unroll
                for (int e = 0; e < 4; ++e) q[e] += hv[d] * wq[d * 4 + e];
            const float SC = 0.72134752044f;   // 0.5 (=1/sqrt(DH)) * log2(e)
            #pragma unroll
            for (int e = 0; e < 4; ++e) q[e] *= SC;

            const float4* kp = reinterpret_cast<const float4*>(kb) + h * 257;
            const float4* vp = reinterpret_cast<const float4*>(vb) + h * 257;
            float lsum = 0.f, o0 = 0.f, o1 = 0.f, o2 = 0.f, o3 = 0.f;
            #pragma unroll 4
            for (int tt = 0; tt < 257; ++tt) {
                const float4 kk = kp[tt];
                const float s2 = q[0] * kk.x + q[1] * kk.y + q[2] * kk.z + q[3] * kk.w;
                const float p = exp2f(s2);
                lsum += p;
                const float4 vv = vp[tt];
                o0 += p * vv.x; o1 += p * vv.y; o2 += p * vv.z; o3 += p * vv.w;
            }
            const float inv = 1.0f / lsum;
            float* xr = xb + s * 9 + h * 4;
            xr[0] += o0 * inv; xr[1] += o1 * inv; xr[2] += o2 * inv; xr[3] += o3 * inv;
        }
        __syncthreads();

        // ---- LN2 ----
        if (t < 257) {
            float v0[8]; float m = 0.f;
            #pragma unroll
            for (int e = 0; e < 8; ++e) { v0[e] = xb[t * 9 + e]; m += v0[e]; }
            m *= 0.125f;
            float var = 0.f;
            #pragma unroll
            for (int e = 0; e < 8; ++e) { float d = v0[e] - m; var += d * d; }
            var *= 0.125f;
            const float rs = rsqrtf(var + 1e-5f);
            const float* g = ln2_g + l * 8; const float* bb = ln2_b + l * 8;
            #pragma unroll
            for (int e = 0; e < 8; ++e) hb[t * 9 + e] = (v0[e] - m) * rs * g[e] + bb[e];
        }
        __syncthreads();

        // ---- MLP (exact-erf GELU) ----
        if (t < 257) {
            float hv[8];
            #pragma unroll
            for (int e = 0; e < 8; ++e) hv[e] = hb[t * 9 + e];
            float acc[8] = {0.f, 0.f, 0.f, 0.f, 0.f, 0.f, 0.f, 0.f};
            const float* w1 = w1s + l * 256; const float* bb1 = b1s + l * 32;
            const float* w2 = w2s + l * 256; const float* bb2 = b2s + l * 8;
            for (int u = 0; u < 32; ++u) {
                float a = bb1[u];
                #pragma unroll
                for (int e = 0; e < 8; ++e) a += hv[e] * w1[e * 32 + u];
                const float gl = 0.5f * a * (1.0f + erff(a * 0.70710678f));
                #pragma unroll
                for (int e = 0; e < 8; ++e) acc[e] += gl * w2[u * 8 + e];
            }
            #pragma unroll
            for (int e = 0; e < 8; ++e) xb[t * 9 + e] += acc[e] + bb2[e];
        }
        __syncthreads();
    }

    // ---- Head: out = x[0] @ Wf + bf ----
    if (t < 10) {
        float a = bf[t];
        #pragma unroll
        for (int e = 0; e < 8; ++e) a += xb[e] * Wf[e * 10 + t];
        out[(size_t)n * 10 + t] = a;
    }
}

extern "C" void kernel_launch(void* const* d_in, const int* in_sizes, int n_in,
                              void* d_out, int out_size, void* d_ws, size_t ws_size,
                              hipStream_t stream) {
    const float* img    = (const float*)d_in[0];
    const int*   labels = (const int*)  d_in[1];
    const float* Wm     = (const float*)d_in[2];
    const float* bm     = (const float*)d_in[3];
    const float* cls    = (const float*)d_in[4];
    const float* pe     = (const float*)d_in[5];
    const float* ln1_g  = (const float*)d_in[6];
    const float* ln1_b  = (const float*)d_in[7];
    const float* Wq     = (const float*)d_in[8];
    const float* bq     = (const float*)d_in[9];
    const float* Wk     = (const float*)d_in[10];
    const float* bk     = (const float*)d_in[11];
    const float* Wv     = (const float*)d_in[12];
    const float* bv     = (const float*)d_in[13];
    const float* ln2_g  = (const float*)d_in[14];
    const float* ln2_b  = (const float*)d_in[15];
    const float* W1     = (const float*)d_in[16];
    const float* b1     = (const float*)d_in[17];
    const float* W2     = (const float*)d_in[18];
    const float* b2     = (const float*)d_in[19];
    const float* Wf     = (const float*)d_in[20];
    const float* bf     = (const float*)d_in[21];
    float* out = (float*)d_out;
    float* xws = (float*)d_ws;                     // 512*257*8 floats = 4.2 MB

    const int n = in_sizes[0] / N_IMG_D;           // 512 images
    k_patch_embed<<<n * 16, 256, 0, stream>>>(img, Wm, bm, pe, xws);
    k_transformer<<<n, 576, 0, stream>>>(xws, labels, cls, pe, ln1_g, ln1_b,
        Wq, bq, Wk, bk, Wv, bv, ln2_g, ln2_b, W1, b1, W2, b2, Wf, bf, out);
}